// Round 1
// baseline (603.715 us; speedup 1.0000x reference)
//
#include <hip/hip_runtime.h>

#define NN 50000      // nodes
#define NF 64         // features
#define NH 512        // hidden
#define NE 800000     // edges

// ---------------------------------------------------------------------------
// detect whether edge_index is int64 (high dwords all zero) or int32
__global__ void detect_idx(const int* __restrict__ ei, int* __restrict__ flag) {
    if (threadIdx.x == 0 && blockIdx.x == 0) {
        int any = 0;
        for (int i = 0; i < 32; ++i) any |= ei[2 * i + 1];
        *flag = (any == 0) ? 1 : 0;   // 1 => int64 layout
    }
}

// h0 = x  (init for scatter accumulate)
__global__ __launch_bounds__(256) void copy_x(const float4* __restrict__ x,
                                              float4* __restrict__ h0) {
    int t = blockIdx.x * 256 + threadIdx.x;
    if (t < NN * NF / 4) h0[t] = x[t];
}

// h0[dst] += x[src] over all edges; one thread per (edge, feature)
__global__ __launch_bounds__(256) void scatter_add(const float* __restrict__ x,
                                                   const void* __restrict__ eiv,
                                                   const int* __restrict__ flag,
                                                   float* __restrict__ h0) {
    long long t = (long long)blockIdx.x * 256 + threadIdx.x;
    int e = (int)(t >> 6);
    int f = (int)(t & 63);
    if (e >= NE) return;
    int src, dst;
    if (*flag) {
        const long long* ei = (const long long*)eiv;
        src = (int)ei[e];
        dst = (int)ei[NE + e];
    } else {
        const int* ei = (const int*)eiv;
        src = ei[e];
        dst = ei[NE + e];
    }
    atomicAdd(&h0[(long long)dst * NF + f], x[(long long)src * NF + f]);
}

// ---------------------------------------------------------------------------
// fp32 GEMM: C[M,N] = A[M,K] @ B[K,N] + bias, optional ReLU.
// 128x128 tile, BK=16, 256 threads, 8x8 per-thread register block.
template <int K, bool RELU>
__global__ __launch_bounds__(256) void gemm_bias(const float* __restrict__ A,
                                                 const float* __restrict__ B,
                                                 const float* __restrict__ bias,
                                                 float* __restrict__ C,
                                                 int M, int N) {
    const int BM = 128, BN = 128, BK = 16;
    __shared__ float As[BK][BM];
    __shared__ float Bs[BK][BN];
    int tid = threadIdx.x;
    int tx = tid & 15, ty = tid >> 4;
    int rbase = blockIdx.x * BM;
    int nbase = blockIdx.y * BN;

    float acc[8][8];
#pragma unroll
    for (int i = 0; i < 8; ++i)
#pragma unroll
        for (int j = 0; j < 8; ++j) acc[i][j] = 0.f;

    for (int kb = 0; kb < K; kb += BK) {
        // stage A tile transposed: As[k][m]
#pragma unroll
        for (int i = 0; i < 2; ++i) {
            int idx = tid * 2 + i;           // 0..511
            int m = idx >> 2, k4 = idx & 3;  // m 0..127, k4 0..3
            float4 v = make_float4(0.f, 0.f, 0.f, 0.f);
            int row = rbase + m;
            if (row < M) v = *(const float4*)&A[(long long)row * K + kb + k4 * 4];
            As[k4 * 4 + 0][m] = v.x;
            As[k4 * 4 + 1][m] = v.y;
            As[k4 * 4 + 2][m] = v.z;
            As[k4 * 4 + 3][m] = v.w;
        }
        // stage B tile: Bs[k][n]
#pragma unroll
        for (int i = 0; i < 2; ++i) {
            int idx = tid * 2 + i;            // 0..511
            int kk = idx >> 5, n4 = idx & 31; // kk 0..15, n4 0..31
            float4 v = *(const float4*)&B[(long long)(kb + kk) * N + nbase + n4 * 4];
            *(float4*)&Bs[kk][n4 * 4] = v;
        }
        __syncthreads();
#pragma unroll
        for (int kk = 0; kk < BK; ++kk) {
            float a[8], b[8];
            *(float4*)&a[0] = *(const float4*)&As[kk][ty * 8];
            *(float4*)&a[4] = *(const float4*)&As[kk][ty * 8 + 4];
            *(float4*)&b[0] = *(const float4*)&Bs[kk][tx * 4];
            *(float4*)&b[4] = *(const float4*)&Bs[kk][tx * 4 + 64];
#pragma unroll
            for (int i = 0; i < 8; ++i)
#pragma unroll
                for (int j = 0; j < 8; ++j)
                    acc[i][j] = fmaf(a[i], b[j], acc[i][j]);
        }
        __syncthreads();
    }

    float4 bb0 = *(const float4*)&bias[nbase + tx * 4];
    float4 bb1 = *(const float4*)&bias[nbase + 64 + tx * 4];
#pragma unroll
    for (int i = 0; i < 8; ++i) {
        int row = rbase + ty * 8 + i;
        if (row >= M) continue;
        float4 o0, o1;
        o0.x = acc[i][0] + bb0.x; o0.y = acc[i][1] + bb0.y;
        o0.z = acc[i][2] + bb0.z; o0.w = acc[i][3] + bb0.w;
        o1.x = acc[i][4] + bb1.x; o1.y = acc[i][5] + bb1.y;
        o1.z = acc[i][6] + bb1.z; o1.w = acc[i][7] + bb1.w;
        if (RELU) {
            o0.x = fmaxf(o0.x, 0.f); o0.y = fmaxf(o0.y, 0.f);
            o0.z = fmaxf(o0.z, 0.f); o0.w = fmaxf(o0.w, 0.f);
            o1.x = fmaxf(o1.x, 0.f); o1.y = fmaxf(o1.y, 0.f);
            o1.z = fmaxf(o1.z, 0.f); o1.w = fmaxf(o1.w, 0.f);
        }
        *(float4*)&C[(long long)row * N + nbase + tx * 4] = o0;
        *(float4*)&C[(long long)row * N + nbase + 64 + tx * 4] = o1;
    }
}

// ---------------------------------------------------------------------------
// per-column sum / sumsq partials via atomics. stats[0..511]=sum, [512..1023]=sumsq
__global__ __launch_bounds__(256) void bn_stats(const float* __restrict__ h2,
                                                float* __restrict__ stats) {
    int tid = threadIdx.x;
    long long base = (long long)blockIdx.x * 128;
    int rmax = min(128, NN - (int)base);
    float s0 = 0.f, q0 = 0.f, s1 = 0.f, q1 = 0.f;
    for (int r = 0; r < rmax; ++r) {
        const float* p = h2 + (base + r) * NH;
        float v0 = p[tid];
        float v1 = p[256 + tid];
        s0 += v0; q0 += v0 * v0;
        s1 += v1; q1 += v1 * v1;
    }
    atomicAdd(&stats[tid], s0);
    atomicAdd(&stats[256 + tid], s1);
    atomicAdd(&stats[512 + tid], q0);
    atomicAdd(&stats[768 + tid], q1);
}

// BN(train stats) + ReLU + classifier (512 -> 2) fused; one wave per row
__global__ __launch_bounds__(256) void bn_cls(const float* __restrict__ h2,
                                              const float* __restrict__ stats,
                                              const float* __restrict__ gamma,
                                              const float* __restrict__ beta,
                                              const float* __restrict__ Wc,
                                              const float* __restrict__ bc,
                                              float* __restrict__ out) {
    __shared__ float scale[NH], shift[NH], wc0[NH], wc1[NH];
    int tid = threadIdx.x;
    for (int c = tid; c < NH; c += 256) {
        float mean = stats[c] * (1.0f / NN);
        float var = stats[NH + c] * (1.0f / NN) - mean * mean;
        float rs = rsqrtf(var + 1e-5f);
        float sc = gamma[c] * rs;
        scale[c] = sc;
        shift[c] = beta[c] - mean * sc;
        wc0[c] = Wc[2 * c];
        wc1[c] = Wc[2 * c + 1];
    }
    __syncthreads();
    int lane = tid & 63;
    int wid = blockIdx.x * 4 + (tid >> 6);
    int nw = gridDim.x * 4;
    float bc0 = bc[0], bc1 = bc[1];
    for (int row = wid; row < NN; row += nw) {
        float a0 = 0.f, a1 = 0.f;
#pragma unroll
        for (int kk = 0; kk < 8; ++kk) {
            int k = kk * 64 + lane;
            float v = h2[(long long)row * NH + k];
            float hn = fmaxf(fmaf(v, scale[k], shift[k]), 0.f);
            a0 = fmaf(hn, wc0[k], a0);
            a1 = fmaf(hn, wc1[k], a1);
        }
#pragma unroll
        for (int off = 32; off; off >>= 1) {
            a0 += __shfl_xor(a0, off);
            a1 += __shfl_xor(a1, off);
        }
        if (lane == 0) {
            out[(long long)row * 2 + 0] = a0 + bc0;
            out[(long long)row * 2 + 1] = a1 + bc1;
        }
    }
}

// ---------------------------------------------------------------------------
extern "C" void kernel_launch(void* const* d_in, const int* in_sizes, int n_in,
                              void* d_out, int out_size, void* d_ws, size_t ws_size,
                              hipStream_t stream) {
    const float* x     = (const float*)d_in[0];
    const void*  ei    = d_in[1];
    const float* W1    = (const float*)d_in[2];
    const float* b1    = (const float*)d_in[3];
    const float* W2    = (const float*)d_in[4];
    const float* b2    = (const float*)d_in[5];
    const float* gamma = (const float*)d_in[6];
    const float* beta  = (const float*)d_in[7];
    const float* Wc    = (const float*)d_in[8];
    const float* bc    = (const float*)d_in[9];
    float* out = (float*)d_out;

    float* ws = (float*)d_ws;
    float* h0    = ws;                                   // 3.2M  floats
    float* h1    = ws + (long long)NN * NF;              // 25.6M floats
    float* h2    = h1 + (long long)NN * NH;              // 25.6M floats
    float* stats = h2 + (long long)NN * NH;              // 1024  floats
    int*   flag  = (int*)(stats + 1024);

    hipMemsetAsync(stats, 0, 1024 * sizeof(float), stream);
    detect_idx<<<1, 1, 0, stream>>>((const int*)ei, flag);
    copy_x<<<(NN * NF / 4 + 255) / 256, 256, 0, stream>>>((const float4*)x, (float4*)h0);
    scatter_add<<<(int)(((long long)NE * 64) / 256), 256, 0, stream>>>(x, ei, flag, h0);

    dim3 g1((NN + 127) / 128, NH / 128);
    gemm_bias<NF, true><<<g1, 256, 0, stream>>>(h0, W1, b1, h1, NN, NH);
    gemm_bias<NH, false><<<g1, 256, 0, stream>>>(h1, W2, b2, h2, NN, NH);

    bn_stats<<<(NN + 127) / 128, 256, 0, stream>>>(h2, stats);
    bn_cls<<<512, 256, 0, stream>>>(h2, stats, gamma, beta, Wc, bc, out);
}

// Round 2
// 339.302 us; speedup vs baseline: 1.7793x; 1.7793x over previous
//
#include <hip/hip_runtime.h>
#include <hip/hip_bf16.h>

#define NN 50000      // nodes
#define MP 50048      // padded nodes (391 * 128)
#define NF 64         // features
#define NH 512        // hidden
#define NE 800000     // edges

typedef __attribute__((ext_vector_type(8))) short bf16x8;
typedef __attribute__((ext_vector_type(4))) float f32x4;

#define GLOAD16(g, l)                                                        \
    __builtin_amdgcn_global_load_lds(                                        \
        (const __attribute__((address_space(1))) unsigned int*)(g),          \
        (__attribute__((address_space(3))) unsigned int*)(l), 16, 0, 0)

// ---------------------------------------------------------------------------
// detect whether edge_index is int64 (high dwords all zero) or int32
__global__ void detect_idx(const int* __restrict__ ei, int* __restrict__ flag) {
    if (threadIdx.x == 0 && blockIdx.x == 0) {
        int any = 0;
        for (int i = 0; i < 32; ++i) any |= ei[2 * i + 1];
        *flag = (any == 0) ? 1 : 0;   // 1 => int64 layout
    }
}

// h0 = x  (init for scatter accumulate)
__global__ __launch_bounds__(256) void copy_x(const float4* __restrict__ x,
                                              float4* __restrict__ h0) {
    int t = blockIdx.x * 256 + threadIdx.x;
    if (t < NN * NF / 4) h0[t] = x[t];
}

// h0[dst] += x[src] over all edges; one thread per (edge, feature)
__global__ __launch_bounds__(256) void scatter_add(const float* __restrict__ x,
                                                   const void* __restrict__ eiv,
                                                   const int* __restrict__ flag,
                                                   float* __restrict__ h0) {
    long long t = (long long)blockIdx.x * 256 + threadIdx.x;
    int e = (int)(t >> 6);
    int f = (int)(t & 63);
    if (e >= NE) return;
    int src, dst;
    if (*flag) {
        const long long* ei = (const long long*)eiv;
        src = (int)ei[e];
        dst = (int)ei[NE + e];
    } else {
        const int* ei = (const int*)eiv;
        src = ei[e];
        dst = ei[NE + e];
    }
    atomicAdd(&h0[(long long)dst * NF + f], x[(long long)src * NF + f]);
}

// h0 (fp32, NN rows) -> h0b (bf16, MP rows, pad rows zeroed)
__global__ __launch_bounds__(256) void cvt_h0(const float* __restrict__ h0,
                                              __hip_bfloat16* __restrict__ h0b) {
    int t = blockIdx.x * 256 + threadIdx.x;
    if (t >= MP * NF / 4) return;
    int row = (t * 4) >> 6;
    if (row < NN) {
        float4 v = *(const float4*)&h0[t * 4];
        h0b[t * 4 + 0] = __float2bfloat16(v.x);
        h0b[t * 4 + 1] = __float2bfloat16(v.y);
        h0b[t * 4 + 2] = __float2bfloat16(v.z);
        h0b[t * 4 + 3] = __float2bfloat16(v.w);
    } else {
        h0b[t * 4 + 0] = __float2bfloat16(0.f);
        h0b[t * 4 + 1] = __float2bfloat16(0.f);
        h0b[t * 4 + 2] = __float2bfloat16(0.f);
        h0b[t * 4 + 3] = __float2bfloat16(0.f);
    }
}

// W [K][N] fp32 -> WT [N][K] bf16
__global__ __launch_bounds__(256) void cvt_wt(const float* __restrict__ W,
                                              __hip_bfloat16* __restrict__ WT,
                                              int K, int N) {
    int t = blockIdx.x * 256 + threadIdx.x;
    if (t >= K * N) return;
    int n = t % N, k = t / N;
    WT[n * K + k] = __float2bfloat16(W[t]);
}

// ---------------------------------------------------------------------------
// bf16 MFMA GEMM (m97 structure): C[MP,512] = A[MP,K] @ BT[512,K]^T + bias
// 128x128 tile, BK=64, 4 waves (2x2), per-wave 64x64 = 4x4 fragments 16x16.
template <int K, bool RELU, bool OUTBF>
__global__ __launch_bounds__(256) void gemm_mfma(const __hip_bfloat16* __restrict__ A,
                                                 const __hip_bfloat16* __restrict__ BT,
                                                 const float* __restrict__ bias,
                                                 void* __restrict__ C) {
    constexpr int BK = 64;
    __shared__ __hip_bfloat16 As[128 * BK];
    __shared__ __hip_bfloat16 Bs[128 * BK];
    const int tid = threadIdx.x;
    const int lane = tid & 63;
    const int w = tid >> 6;          // wave 0..3
    const int wm = w >> 1, wn = w & 1;
    const long long rbase = (long long)blockIdx.x * 128;
    const int nbase = blockIdx.y * 128;

    f32x4 acc[4][4];
#pragma unroll
    for (int i = 0; i < 4; ++i)
#pragma unroll
        for (int j = 0; j < 4; ++j) acc[i][j] = (f32x4){0.f, 0.f, 0.f, 0.f};

    for (int kb = 0; kb < K; kb += BK) {
        // stage: wave w loads 32 rows of A-tile and 32 rows of BT-tile.
        // each global_load_lds call moves 1KB = 8 rows x 128B (lane>>3 = row, lane&7 = 16B seg)
        const __hip_bfloat16* ga =
            A + (rbase + w * 32 + (lane >> 3)) * (long long)K + kb + (lane & 7) * 8;
        const __hip_bfloat16* gb =
            BT + (long long)(nbase + w * 32 + (lane >> 3)) * K + kb + (lane & 7) * 8;
        __hip_bfloat16* la = As + (w * 32) * BK;   // wave-uniform LDS base
        __hip_bfloat16* lb = Bs + (w * 32) * BK;
#pragma unroll
        for (int t = 0; t < 4; ++t) {
            GLOAD16(ga + (long long)t * 8 * K, la + t * 8 * BK);
            GLOAD16(gb + (long long)t * 8 * K, lb + t * 8 * BK);
        }
        __syncthreads();   // drains vmcnt (compiler emits waitcnt before barrier)

#pragma unroll
        for (int ks = 0; ks < 2; ++ks) {
            bf16x8 af[4], bfr[4];
#pragma unroll
            for (int mi = 0; mi < 4; ++mi)
                af[mi] = *(const bf16x8*)&As[(wm * 64 + mi * 16 + (lane & 15)) * BK +
                                            ks * 32 + (lane >> 4) * 8];
#pragma unroll
            for (int ni = 0; ni < 4; ++ni)
                bfr[ni] = *(const bf16x8*)&Bs[(wn * 64 + ni * 16 + (lane & 15)) * BK +
                                             ks * 32 + (lane >> 4) * 8];
#pragma unroll
            for (int mi = 0; mi < 4; ++mi)
#pragma unroll
                for (int ni = 0; ni < 4; ++ni)
                    acc[mi][ni] = __builtin_amdgcn_mfma_f32_16x16x32_bf16(
                        af[mi], bfr[ni], acc[mi][ni], 0, 0, 0);
        }
        __syncthreads();
    }

    // epilogue: C/D layout col=lane&15, row=(lane>>4)*4+reg
    const int col0 = nbase + wn * 64 + (lane & 15);
    const long long row00 = rbase + wm * 64 + (lane >> 4) * 4;
#pragma unroll
    for (int ni = 0; ni < 4; ++ni) {
        int col = col0 + ni * 16;
        float bv = bias[col];
#pragma unroll
        for (int mi = 0; mi < 4; ++mi) {
            long long r0 = row00 + mi * 16;
#pragma unroll
            for (int r = 0; r < 4; ++r) {
                float v = acc[mi][ni][r] + bv;
                if (RELU) v = fmaxf(v, 0.f);
                if (OUTBF)
                    ((__hip_bfloat16*)C)[(r0 + r) * NH + col] = __float2bfloat16(v);
                else
                    ((float*)C)[(r0 + r) * NH + col] = v;
            }
        }
    }
}

// ---------------------------------------------------------------------------
// per-column sum / sumsq partials via atomics. stats[0..511]=sum, [512..1023]=sumsq
__global__ __launch_bounds__(256) void bn_stats(const float* __restrict__ h2,
                                                float* __restrict__ stats) {
    int tid = threadIdx.x;
    long long base = (long long)blockIdx.x * 128;
    int rmax = min(128, NN - (int)base);
    float s0 = 0.f, q0 = 0.f, s1 = 0.f, q1 = 0.f;
    for (int r = 0; r < rmax; ++r) {
        const float* p = h2 + (base + r) * NH;
        float v0 = p[tid];
        float v1 = p[256 + tid];
        s0 += v0; q0 += v0 * v0;
        s1 += v1; q1 += v1 * v1;
    }
    atomicAdd(&stats[tid], s0);
    atomicAdd(&stats[256 + tid], s1);
    atomicAdd(&stats[512 + tid], q0);
    atomicAdd(&stats[768 + tid], q1);
}

// BN(train stats) + ReLU + classifier (512 -> 2) fused; one wave per row
__global__ __launch_bounds__(256) void bn_cls(const float* __restrict__ h2,
                                              const float* __restrict__ stats,
                                              const float* __restrict__ gamma,
                                              const float* __restrict__ beta,
                                              const float* __restrict__ Wc,
                                              const float* __restrict__ bc,
                                              float* __restrict__ out) {
    __shared__ float scale[NH], shift[NH], wc0[NH], wc1[NH];
    int tid = threadIdx.x;
    for (int c = tid; c < NH; c += 256) {
        float mean = stats[c] * (1.0f / NN);
        float var = stats[NH + c] * (1.0f / NN) - mean * mean;
        float rs = rsqrtf(var + 1e-5f);
        float sc = gamma[c] * rs;
        scale[c] = sc;
        shift[c] = beta[c] - mean * sc;
        wc0[c] = Wc[2 * c];
        wc1[c] = Wc[2 * c + 1];
    }
    __syncthreads();
    int lane = tid & 63;
    int wid = blockIdx.x * 4 + (tid >> 6);
    int nw = gridDim.x * 4;
    float bc0 = bc[0], bc1 = bc[1];
    for (int row = wid; row < NN; row += nw) {
        float a0 = 0.f, a1 = 0.f;
#pragma unroll
        for (int kk = 0; kk < 8; ++kk) {
            int k = kk * 64 + lane;
            float v = h2[(long long)row * NH + k];
            float hn = fmaxf(fmaf(v, scale[k], shift[k]), 0.f);
            a0 = fmaf(hn, wc0[k], a0);
            a1 = fmaf(hn, wc1[k], a1);
        }
#pragma unroll
        for (int off = 32; off; off >>= 1) {
            a0 += __shfl_xor(a0, off);
            a1 += __shfl_xor(a1, off);
        }
        if (lane == 0) {
            out[(long long)row * 2 + 0] = a0 + bc0;
            out[(long long)row * 2 + 1] = a1 + bc1;
        }
    }
}

// ---------------------------------------------------------------------------
extern "C" void kernel_launch(void* const* d_in, const int* in_sizes, int n_in,
                              void* d_out, int out_size, void* d_ws, size_t ws_size,
                              hipStream_t stream) {
    const float* x     = (const float*)d_in[0];
    const void*  ei    = d_in[1];
    const float* W1    = (const float*)d_in[2];
    const float* b1    = (const float*)d_in[3];
    const float* W2    = (const float*)d_in[4];
    const float* b2    = (const float*)d_in[5];
    const float* gamma = (const float*)d_in[6];
    const float* beta  = (const float*)d_in[7];
    const float* Wc    = (const float*)d_in[8];
    const float* bc    = (const float*)d_in[9];
    float* out = (float*)d_out;

    // workspace carve-up (256B aligned)
    char* base = (char*)d_ws;
    size_t o = 0;
    auto alloc = [&](size_t bytes) {
        char* p = base + o;
        o = (o + bytes + 255) & ~(size_t)255;
        return p;
    };
    float*          h0    = (float*)alloc((size_t)MP * NF * 4);
    float*          h2    = (float*)alloc((size_t)MP * NH * 4);
    float*          stats = (float*)alloc(1024 * 4);
    __hip_bfloat16* h0b   = (__hip_bfloat16*)alloc((size_t)MP * NF * 2);
    __hip_bfloat16* h1b   = (__hip_bfloat16*)alloc((size_t)MP * NH * 2);
    __hip_bfloat16* w1t   = (__hip_bfloat16*)alloc((size_t)NH * NF * 2);
    __hip_bfloat16* w2t   = (__hip_bfloat16*)alloc((size_t)NH * NH * 2);
    int*            flag  = (int*)alloc(256);

    hipMemsetAsync(stats, 0, 1024 * sizeof(float), stream);
    detect_idx<<<1, 1, 0, stream>>>((const int*)ei, flag);
    copy_x<<<(NN * NF / 4 + 255) / 256, 256, 0, stream>>>((const float4*)x, (float4*)h0);
    scatter_add<<<(int)(((long long)NE * 64) / 256), 256, 0, stream>>>(x, ei, flag, h0);

    cvt_h0<<<(MP * NF / 4 + 255) / 256, 256, 0, stream>>>(h0, h0b);
    cvt_wt<<<(NF * NH + 255) / 256, 256, 0, stream>>>(W1, w1t, NF, NH);
    cvt_wt<<<(NH * NH + 255) / 256, 256, 0, stream>>>(W2, w2t, NH, NH);

    dim3 g(MP / 128, NH / 128);
    gemm_mfma<NF, true, true><<<g, 256, 0, stream>>>(h0b, w1t, b1, h1b);
    gemm_mfma<NH, false, false><<<g, 256, 0, stream>>>(h1b, w2t, b2, h2);

    bn_stats<<<(NN + 127) / 128, 256, 0, stream>>>(h2, stats);
    bn_cls<<<512, 256, 0, stream>>>(h2, stats, gamma, beta, Wc, bc, out);
}